// Round 1
// baseline (670.987 us; speedup 1.0000x reference)
//
#include <hip/hip_runtime.h>
#include <hip/hip_bf16.h>

// Problem constants
#define IMG   224
#define PS    16
#define GDIM  14      // IMG/PS
#define NPATCH 196    // GDIM*GDIM
#define CIN   3
#define NCOUT 768
#define NB    64      // batch
#define KDIM  768     // CIN*PS*PS

// Tiling
#define BK    64
#define BN    128
#define LDA   72      // padded LDS stride in bf16 elements (144 B, 16B-multiple)

using short8  = __attribute__((ext_vector_type(8))) short;
using floatx4 = __attribute__((ext_vector_type(4))) float;

static __device__ __forceinline__ short f2bf(float f) {
    __hip_bfloat16 h = __float2bfloat16(f);
    return *reinterpret_cast<short*>(&h);
}

// GEMM per (patch, o-tile): C[64,128] = A[64,768] * W[p, o0:o0+128, :]^T + bias
// Writes either ws in [b][p][o] layout (coalesced) or d_out directly (fallback).
__global__ __launch_bounds__(256)
void dynconv_gemm(const float* __restrict__ x,
                  const float* __restrict__ W,
                  const float* __restrict__ bias,
                  float* __restrict__ dst,
                  int use_ws) {
    __shared__ __align__(16) short As[NB][LDA];     // 64 x 64 chunk (bf16 bits)
    __shared__ __align__(16) short Bs[BN][LDA];     // 128 x 64 chunk

    const int tid = threadIdx.x;
    const int p   = blockIdx.x / 6;
    const int no  = blockIdx.x % 6;
    const int o0  = no * BN;

    const int gi = p / GDIM;
    const int gj = p % GDIM;

    const int lane = tid & 63;
    const int wv   = tid >> 6;        // 0..3, wave id
    const int row  = lane & 15;
    const int quad = lane >> 4;       // 0..3

    floatx4 acc[4][2] = {};           // 4 m-tiles x 2 n-tiles per wave

    // Staging thread mapping (same every chunk)
    const int c4 = (tid & 15) << 2;   // k column within chunk, 0..60, step 4
    const int rb = tid >> 4;          // row base 0..15

    const float* Wp = W + ((size_t)p * NCOUT + o0) * KDIM;

    for (int kk = 0; kk < KDIM; kk += BK) {
        __syncthreads();   // protect LDS from previous iteration's readers

        // ---- stage A: x patch pixels -> As (bf16) ----
        {
            const int kg  = kk + c4;
            const int ch  = kg >> 8;          // channel
            const int rem = kg & 255;
            const int pi  = rem >> 4;
            const int pj  = rem & 15;
            const int rowoff = (gi * PS + pi) * IMG + gj * PS + pj;
            #pragma unroll
            for (int i = 0; i < 4; ++i) {
                const int m = rb + (i << 4);
                const float4 v = *(const float4*)(x + (size_t)(m * CIN + ch) * (IMG * IMG) + rowoff);
                short* d = &As[m][c4];
                d[0] = f2bf(v.x); d[1] = f2bf(v.y); d[2] = f2bf(v.z); d[3] = f2bf(v.w);
            }
        }

        // ---- stage B: W rows -> Bs (bf16) ----
        {
            const float* wsrc = Wp + kk + c4;
            #pragma unroll
            for (int i = 0; i < 8; ++i) {
                const int n = rb + (i << 4);
                const float4 v = *(const float4*)(wsrc + (size_t)n * KDIM);
                short* d = &Bs[n][c4];
                d[0] = f2bf(v.x); d[1] = f2bf(v.y); d[2] = f2bf(v.z); d[3] = f2bf(v.w);
            }
        }

        __syncthreads();

        // ---- MFMA over this K-chunk (2 k-steps of 32) ----
        #pragma unroll
        for (int ks = 0; ks < 2; ++ks) {
            short8 a[4], bf[2];
            const int kofs = ks * 32 + quad * 8;
            #pragma unroll
            for (int mt = 0; mt < 4; ++mt)
                a[mt] = *(const short8*)&As[mt * 16 + row][kofs];
            #pragma unroll
            for (int nt = 0; nt < 2; ++nt)
                bf[nt] = *(const short8*)&Bs[wv * 32 + nt * 16 + row][kofs];
            #pragma unroll
            for (int mt = 0; mt < 4; ++mt)
                #pragma unroll
                for (int nt = 0; nt < 2; ++nt)
                    acc[mt][nt] = __builtin_amdgcn_mfma_f32_16x16x32_bf16(
                        a[mt], bf[nt], acc[mt][nt], 0, 0, 0);
        }
    }

    // ---- epilogue: bias + store ----
    // C/D layout: row m = quad*4 + reg, col n = lane&15  (per 16x16 tile)
    #pragma unroll
    for (int mt = 0; mt < 4; ++mt) {
        #pragma unroll
        for (int nt = 0; nt < 2; ++nt) {
            const int n = wv * 32 + nt * 16 + row;
            const int o = o0 + n;
            const float bv = bias[p * NCOUT + o];
            #pragma unroll
            for (int r = 0; r < 4; ++r) {
                const int m = mt * 16 + quad * 4 + r;
                const float val = acc[mt][nt][r] + bv;
                if (use_ws) {
                    // [b][p][o] layout: coalesced over o
                    dst[((size_t)m * NPATCH + p) * NCOUT + o] = val;
                } else {
                    // direct [b][o][p] layout: scattered (fallback)
                    dst[((size_t)m * NCOUT + o) * NPATCH + p] = val;
                }
            }
        }
    }
}

// Transpose ws [b][p][o] -> out [b][o][p], 32x32 LDS tiles.
__global__ __launch_bounds__(256)
void dynconv_transpose(const float* __restrict__ ws, float* __restrict__ out) {
    __shared__ float tile[32][33];
    const int b  = blockIdx.z;
    const int p0 = blockIdx.x * 32;
    const int o0 = blockIdx.y * 32;
    const int tid = threadIdx.x;
    const int c  = tid & 31;
    const int r0 = tid >> 5;   // 0..7

    const float* src = ws  + (size_t)b * NPATCH * NCOUT;
    float*       dst = out + (size_t)b * NPATCH * NCOUT;

    #pragma unroll
    for (int i = 0; i < 4; ++i) {
        const int pr = p0 + r0 + i * 8;
        if (pr < NPATCH)
            tile[r0 + i * 8][c] = src[(size_t)pr * NCOUT + o0 + c];
    }
    __syncthreads();
    #pragma unroll
    for (int i = 0; i < 4; ++i) {
        const int orow = o0 + r0 + i * 8;
        const int pc = p0 + c;
        if (pc < NPATCH)
            dst[(size_t)orow * NPATCH + pc] = tile[c][r0 + i * 8];
    }
}

extern "C" void kernel_launch(void* const* d_in, const int* in_sizes, int n_in,
                              void* d_out, int out_size, void* d_ws, size_t ws_size,
                              hipStream_t stream) {
    const float* x    = (const float*)d_in[0];
    const float* W    = (const float*)d_in[1];
    const float* bias = (const float*)d_in[2];
    float* out = (float*)d_out;

    const size_t need = (size_t)NB * NPATCH * NCOUT * sizeof(float);  // 38.5 MB
    const int use_ws = (d_ws != nullptr && ws_size >= need) ? 1 : 0;
    float* ws = (float*)d_ws;

    dynconv_gemm<<<dim3(NPATCH * 6), dim3(256), 0, stream>>>(
        x, W, bias, use_ws ? ws : out, use_ws);

    if (use_ws) {
        dynconv_transpose<<<dim3(7, 24, 64), dim3(256), 0, stream>>>(ws, out);
    }
}

// Round 2
// 659.004 us; speedup vs baseline: 1.0182x; 1.0182x over previous
//
#include <hip/hip_runtime.h>
#include <hip/hip_bf16.h>

// Problem constants
#define IMG   224
#define PS    16
#define GDIM  14      // IMG/PS
#define NPATCH 196    // GDIM*GDIM
#define CIN   3
#define NCOUT 768
#define NB    64      // batch
#define KDIM  768     // CIN*PS*PS

// Tiling
#define BK    64
#define BN    128
#define LDA   72      // padded LDS stride in bf16 elements (144 B, 16B-multiple)

using short8  = __attribute__((ext_vector_type(8))) short;
using floatx4 = __attribute__((ext_vector_type(4))) float;

// Pack float4 -> 4 bf16 (RNE) as uint2 for one 8B LDS store.
static __device__ __forceinline__ uint2 pk4(float4 v) {
    __hip_bfloat162 lo = __float22bfloat162_rn(make_float2(v.x, v.y));
    __hip_bfloat162 hi = __float22bfloat162_rn(make_float2(v.z, v.w));
    uint2 r;
    r.x = *reinterpret_cast<unsigned int*>(&lo);
    r.y = *reinterpret_cast<unsigned int*>(&hi);
    return r;
}

// GEMM per (patch, o-tile): C[64,128] = A[64,768] * W[p, o0:o0+128, :]^T + bias
// ws path: writes bf16 [b][p][o] (coalesced); fallback: fp32 scatter to d_out.
__global__ __launch_bounds__(256)
void dynconv_gemm(const float* __restrict__ x,
                  const float* __restrict__ W,
                  const float* __restrict__ bias,
                  __hip_bfloat16* __restrict__ ws,
                  float* __restrict__ out,
                  int use_ws) {
    __shared__ __align__(16) short As[NB][LDA];     // 64 x 64 chunk (bf16 bits)
    __shared__ __align__(16) short Bs[BN][LDA];     // 128 x 64 chunk

    const int tid = threadIdx.x;
    const int p   = blockIdx.x / 6;
    const int no  = blockIdx.x % 6;
    const int o0  = no * BN;

    const int gi = p / GDIM;
    const int gj = p % GDIM;

    const int lane = tid & 63;
    const int wv   = tid >> 6;        // 0..3, wave id
    const int row  = lane & 15;
    const int quad = lane >> 4;       // 0..3

    floatx4 acc[4][2] = {};           // 4 m-tiles x 2 n-tiles per wave

    // Staging thread mapping (same every chunk)
    const int c4 = (tid & 15) << 2;   // k column within chunk, 0..60, step 4
    const int rb = tid >> 4;          // row base 0..15

    const float* Wp = W + ((size_t)p * NCOUT + o0) * KDIM;

    float4 ra[4];     // A prefetch regs
    float4 rbv[8];    // B prefetch regs

    auto loadA = [&](int kk) {
        const int kg  = kk + c4;
        const int ch  = kg >> 8;          // channel
        const int rem = kg & 255;
        const int rowoff = (gi * PS + (rem >> 4)) * IMG + gj * PS + (rem & 15);
        #pragma unroll
        for (int i = 0; i < 4; ++i) {
            const int m = rb + (i << 4);
            ra[i] = *(const float4*)(x + (size_t)(m * CIN + ch) * (IMG * IMG) + rowoff);
        }
    };
    auto loadB = [&](int kk) {
        const float* wsrc = Wp + kk + c4;
        #pragma unroll
        for (int i = 0; i < 8; ++i)
            rbv[i] = *(const float4*)(wsrc + (size_t)(rb + (i << 4)) * KDIM);
    };

    // Prologue: prefetch first chunk into registers
    loadA(0);
    loadB(0);

    for (int kk = 0; kk < KDIM; kk += BK) {
        __syncthreads();   // previous iteration's LDS readers done

        // ---- convert + store prefetched regs to LDS (packed, 8B stores) ----
        #pragma unroll
        for (int i = 0; i < 4; ++i)
            *(uint2*)&As[rb + (i << 4)][c4] = pk4(ra[i]);
        #pragma unroll
        for (int i = 0; i < 8; ++i)
            *(uint2*)&Bs[rb + (i << 4)][c4] = pk4(rbv[i]);

        // ---- issue next chunk's global loads (overlap with MFMA below) ----
        if (kk + BK < KDIM) {
            loadA(kk + BK);
            loadB(kk + BK);
        }

        __syncthreads();

        // ---- MFMA over this K-chunk (2 k-steps of 32) ----
        #pragma unroll
        for (int ks = 0; ks < 2; ++ks) {
            short8 a[4], bf[2];
            const int kofs = ks * 32 + quad * 8;
            #pragma unroll
            for (int mt = 0; mt < 4; ++mt)
                a[mt] = *(const short8*)&As[mt * 16 + row][kofs];
            #pragma unroll
            for (int nt = 0; nt < 2; ++nt)
                bf[nt] = *(const short8*)&Bs[wv * 32 + nt * 16 + row][kofs];
            #pragma unroll
            for (int mt = 0; mt < 4; ++mt)
                #pragma unroll
                for (int nt = 0; nt < 2; ++nt)
                    acc[mt][nt] = __builtin_amdgcn_mfma_f32_16x16x32_bf16(
                        a[mt], bf[nt], acc[mt][nt], 0, 0, 0);
        }
    }

    // ---- epilogue: bias + store ----
    // C/D layout: row m = quad*4 + reg, col n = lane&15  (per 16x16 tile)
    #pragma unroll
    for (int mt = 0; mt < 4; ++mt) {
        #pragma unroll
        for (int nt = 0; nt < 2; ++nt) {
            const int n = wv * 32 + nt * 16 + row;
            const int o = o0 + n;
            const float bv = bias[p * NCOUT + o];
            #pragma unroll
            for (int r = 0; r < 4; ++r) {
                const int m = mt * 16 + quad * 4 + r;
                const float val = acc[mt][nt][r] + bv;
                if (use_ws) {
                    // bf16 [b][p][o] layout: coalesced over o
                    ws[((size_t)m * NPATCH + p) * NCOUT + o] = __float2bfloat16(val);
                } else {
                    // direct fp32 [b][o][p] layout: scattered (fallback)
                    out[((size_t)m * NCOUT + o) * NPATCH + p] = val;
                }
            }
        }
    }
}

// Transpose ws bf16 [b][p][o] -> out fp32 [b][o][p], 32(p) x 64(o) LDS tiles.
__global__ __launch_bounds__(256)
void dynconv_transpose(const __hip_bfloat16* __restrict__ ws,
                       float* __restrict__ out) {
    __shared__ float tile[32][65];    // [p][o], pad 65 -> conflict-free
    const int b  = blockIdx.z;
    const int p0 = blockIdx.x * 32;
    const int o0 = blockIdx.y * 64;
    const int tid = threadIdx.x;

    // Read phase: 32 lanes cover 64 o via bf16x2; 8 p-rows per pass.
    {
        const int cc = tid & 31;          // o-pair index
        const int rr = tid >> 5;          // 0..7
        #pragma unroll
        for (int i = 0; i < 4; ++i) {
            const int pr = p0 + rr + i * 8;
            if (pr < NPATCH) {
                const __hip_bfloat162 v = *(const __hip_bfloat162*)
                    &ws[((size_t)b * NPATCH + pr) * NCOUT + o0 + 2 * cc];
                tile[rr + i * 8][2 * cc]     = __bfloat162float(v.x);
                tile[rr + i * 8][2 * cc + 1] = __bfloat162float(v.y);
            }
        }
    }
    __syncthreads();
    // Write phase: 32 lanes cover 32 p (contiguous); 8 o-rows per pass.
    {
        const int c = tid & 31;           // p offset
        const int r = tid >> 5;           // 0..7
        const int pc = p0 + c;
        if (pc < NPATCH) {
            #pragma unroll
            for (int i = 0; i < 8; ++i) {
                const int orow = o0 + r + i * 8;
                out[((size_t)b * NCOUT + orow) * NPATCH + pc] = tile[c][r + i * 8];
            }
        }
    }
}

extern "C" void kernel_launch(void* const* d_in, const int* in_sizes, int n_in,
                              void* d_out, int out_size, void* d_ws, size_t ws_size,
                              hipStream_t stream) {
    const float* x    = (const float*)d_in[0];
    const float* W    = (const float*)d_in[1];
    const float* bias = (const float*)d_in[2];
    float* out = (float*)d_out;

    const size_t need = (size_t)NB * NPATCH * NCOUT * sizeof(__hip_bfloat16); // 19.3 MB
    const int use_ws = (d_ws != nullptr && ws_size >= need) ? 1 : 0;
    __hip_bfloat16* ws = (__hip_bfloat16*)d_ws;

    dynconv_gemm<<<dim3(NPATCH * 6), dim3(256), 0, stream>>>(
        x, W, bias, ws, out, use_ws);

    if (use_ws) {
        dynconv_transpose<<<dim3(7, 12, 64), dim3(256), 0, stream>>>(ws, out);
    }
}